// Round 7
// baseline (1962.360 us; speedup 1.0000x reference)
//
#include <hip/hip_runtime.h>
#include <hip/hip_bf16.h>

#define B_  32
#define H_  8
#define L_  4096
#define D_  64
#define BH_ 256
#define U_  45
#define UP_ 48

typedef float f32x4  __attribute__((ext_vector_type(4)));
typedef short bf16x8 __attribute__((ext_vector_type(8)));

__device__ __forceinline__ unsigned short f2bf(float f) {
  unsigned u = __builtin_bit_cast(unsigned, f);
  u += 0x7fffu + ((u >> 16) & 1u);   // RNE; inputs finite
  return (unsigned short)(u >> 16);
}

// ---------------------------------------------------------------------------
// Kernel 1: M[bh][q] = max_j(Q·K[idx_j]) - mean_j(Q·K[idx_j]), f32.
// SPATIAL parallelism (the R2/R3/R6 lesson: the compiler sinks/spills any
// register-resident temporal pipeline): one wave per query, lane j owns
// sampled row j (j=0..44; lanes 45-63 clamped+masked). All 45 row loads are
// mutually independent inside ONE basic block -- nothing to software-
// pipeline, ~45x16B natural MLP per query, zero multi-buffer register state.
// Q is broadcast from an 8KB LDS tile (same-address ds_read_b128 = free
// broadcast). Latency hidden by TLP (32 waves/CU); binding resource is the
// L1/L2 gather bandwidth (~47MB/CU / ~60B/cyc ~= 320us floor).
// XCD-affine bh ordering keeps each XCD's K gather (~1MB/bh) L2-resident.
// ---------------------------------------------------------------------------
__global__ __launch_bounds__(256) void k_probM(
    const float* __restrict__ Qg, const float* __restrict__ Kg,
    const int* __restrict__ idxg, float* __restrict__ Mg)
{
  const int blk   = blockIdx.x;          // 32768 blocks
  const int xcd   = blk & 7;
  const int rr    = blk >> 3;            // 0..4095
  const int bhi   = rr >> 7;             // 0..31
  const int chunk = rr & 127;            // 0..127
  const int bh    = xcd + (bhi << 3);
  const int q0    = chunk * 32;          // 32 queries per block

  const int wave = threadIdx.x >> 6;     // 0..3
  const int lane = threadIdx.x & 63;
  const int j    = (lane < U_) ? lane : (U_ - 1);

  __shared__ float qbuf[32][64];         // 8 KB: this block's Q rows
  {
    const f32x4* src = (const f32x4*)(Qg + ((size_t)bh * L_ + q0) * D_);
    f32x4* dst = (f32x4*)qbuf;
    for (int i = threadIdx.x; i < 32 * 64 / 4; i += 256) dst[i] = src[i];
  }
  __syncthreads();

  const float* Kb = Kg + (size_t)bh * (L_ * D_);

  for (int qi = 0; qi < 8; qi++) {
    const int qq = wave * 8 + qi;        // 0..31
    const int q  = q0 + qq;

    const int kid = idxg[(size_t)q * U_ + j];
    const float* kr = Kb + (size_t)kid * D_;

    float dacc = 0.f;
#pragma unroll
    for (int c = 0; c < 4; c++) {        // 16 dims per pass = 1 cache line
      f32x4 k0 = *(const f32x4*)(kr + c * 16);
      f32x4 k1 = *(const f32x4*)(kr + c * 16 + 4);
      f32x4 k2 = *(const f32x4*)(kr + c * 16 + 8);
      f32x4 k3 = *(const f32x4*)(kr + c * 16 + 12);
      const float* qp = &qbuf[qq][c * 16];
      f32x4 p0 = *(const f32x4*)(qp);
      f32x4 p1 = *(const f32x4*)(qp + 4);
      f32x4 p2 = *(const f32x4*)(qp + 8);
      f32x4 p3 = *(const f32x4*)(qp + 12);
      dacc = fmaf(k0[0], p0[0], dacc); dacc = fmaf(k0[1], p0[1], dacc);
      dacc = fmaf(k0[2], p0[2], dacc); dacc = fmaf(k0[3], p0[3], dacc);
      dacc = fmaf(k1[0], p1[0], dacc); dacc = fmaf(k1[1], p1[1], dacc);
      dacc = fmaf(k1[2], p1[2], dacc); dacc = fmaf(k1[3], p1[3], dacc);
      dacc = fmaf(k2[0], p2[0], dacc); dacc = fmaf(k2[1], p2[1], dacc);
      dacc = fmaf(k2[2], p2[2], dacc); dacc = fmaf(k2[3], p2[3], dacc);
      dacc = fmaf(k3[0], p3[0], dacc); dacc = fmaf(k3[1], p3[1], dacc);
      dacc = fmaf(k3[2], p3[2], dacc); dacc = fmaf(k3[3], p3[3], dacc);
    }

    float mxv = (lane < U_) ? dacc : -3.4e38f;
    float smv = (lane < U_) ? dacc : 0.f;
#pragma unroll
    for (int off = 1; off < 64; off <<= 1) {
      mxv = fmax(mxv, __shfl_xor(mxv, off));
      smv += __shfl_xor(smv, off);
    }
    if (lane == 0) Mg[(size_t)bh * L_ + q] = mxv - smv * (1.0f / 45.0f);
  }
}

// ---------------------------------------------------------------------------
// Kernel 2: top-45 indices per (b,h) via 45 iterative block argmax passes.
// Writes 48 entries (3 pads = sels[0], harmlessly recomputed in k_attn).
// ---------------------------------------------------------------------------
__global__ __launch_bounds__(256) void k_top45(
    const float* __restrict__ Mg, int* __restrict__ qselg)
{
  __shared__ float mv[L_];
  __shared__ float rv[256];
  __shared__ int   ri[256];
  __shared__ int   sels[UP_];
  const int bh = blockIdx.x, t = threadIdx.x;

  for (int i = t; i < L_; i += 256) mv[i] = Mg[(size_t)bh * L_ + i];
  __syncthreads();

  for (int it = 0; it < U_; it++) {
    float bv = -3.4e38f; int bi = 0;
    for (int i = t; i < L_; i += 256) {
      float v = mv[i];
      if (v > bv) { bv = v; bi = i; }
    }
    rv[t] = bv; ri[t] = bi;
    __syncthreads();
    for (int s = 128; s > 0; s >>= 1) {
      if (t < s) {
        float ov = rv[t + s];
        if (ov > rv[t] || (ov == rv[t] && ri[t + s] < ri[t])) {
          rv[t] = ov; ri[t] = ri[t + s];
        }
      }
      __syncthreads();
    }
    if (t == 0) { sels[it] = ri[0]; mv[ri[0]] = -3.4e38f; }
    __syncthreads();
  }
  if (t == 0) { sels[45] = sels[0]; sels[46] = sels[0]; sels[47] = sels[0]; }
  __syncthreads();
  if (t < UP_) qselg[bh * UP_ + t] = sels[t];
}

// ---------------------------------------------------------------------------
// Kernel 3: context = cumsum(V, axis=L), written transposed to out[b,l,h,d].
// 8 L-segments x 64 dims per block; two-pass (seg sums -> prefixed scan).
// ---------------------------------------------------------------------------
__global__ __launch_bounds__(512) void k_cumsum(
    const float* __restrict__ Vg, float* __restrict__ out)
{
  const int bh = blockIdx.x, b = bh >> 3, h = bh & 7;
  const int d = threadIdx.x & 63, s = threadIdx.x >> 6;   // 8 segs x 512 rows
  __shared__ float segsum[8][64];

  const float* vb = Vg + (size_t)bh * L_ * D_ + d;
  const int l0 = s * 512;

  float acc = 0.f;
  for (int l = l0; l < l0 + 512; l += 4) {
    float a0 = vb[(size_t)(l + 0) * D_];
    float a1 = vb[(size_t)(l + 1) * D_];
    float a2 = vb[(size_t)(l + 2) * D_];
    float a3 = vb[(size_t)(l + 3) * D_];
    acc += a0; acc += a1; acc += a2; acc += a3;
  }
  segsum[s][d] = acc;
  __syncthreads();

  float run = 0.f;
  for (int ss = 0; ss < s; ss++) run += segsum[ss][d];

  float* ob = out + ((size_t)b * L_ * H_ + h) * D_ + d;
  for (int l = l0; l < l0 + 512; l += 4) {
    float a0 = vb[(size_t)(l + 0) * D_];
    float a1 = vb[(size_t)(l + 1) * D_];
    float a2 = vb[(size_t)(l + 2) * D_];
    float a3 = vb[(size_t)(l + 3) * D_];
    run += a0; ob[(size_t)(l + 0) * (H_ * D_)] = run;
    run += a1; ob[(size_t)(l + 1) * (H_ * D_)] = run;
    run += a2; ob[(size_t)(l + 2) * (H_ * D_)] = run;
    run += a3; ob[(size_t)(l + 3) * (H_ * D_)] = run;
  }
}

// ---------------------------------------------------------------------------
// Kernel 4: flash attention for the 45 selected rows per (b,h), bf16 MFMA.
// 8 waves split the 4096 keys (512 each); per-wave online softmax; P is
// moved C-frag -> A-frag through a padded per-wave LDS buffer; deterministic
// barrier-serialized cross-wave combine; overwrite rows of `out`.
// mask value -1e30; dead-row guard: p *= (m_row > -1e29).
// ---------------------------------------------------------------------------
__global__ __launch_bounds__(512, 2) void k_attn(
    const float* __restrict__ Qg, const float* __restrict__ Kg,
    const float* __restrict__ Vg, const int* __restrict__ qselg,
    float* __restrict__ out)
{
  const int bh = blockIdx.x, b = bh >> 3, h = bh & 7;
  const int wave = threadIdx.x >> 6, lane = threadIdx.x & 63;
  const int l15 = lane & 15, l4 = lane >> 4;

  __shared__ int   qs[UP_];
  __shared__ float mw[8][UP_];
  __shared__ float lw[8][UP_];
  __shared__ float lgf[UP_];
  __shared__ float Osum[UP_][64];
  __shared__ unsigned short Pl[8][16][72];   // per-wave P tile, padded stride 72

  if (threadIdx.x < UP_) qs[threadIdx.x] = qselg[bh * UP_ + threadIdx.x];
  for (int i = threadIdx.x; i < UP_ * 64; i += 512) (&Osum[0][0])[i] = 0.f;
  __syncthreads();

  int qmax = 0;
  for (int r2 = 0; r2 < UP_; r2++) qmax = max(qmax, qs[r2]);

  const float* Qb = Qg + (size_t)bh * L_ * D_;
  const float* Kb = Kg + (size_t)bh * L_ * D_;
  const float* Vb = Vg + (size_t)bh * L_ * D_;

  // A-frags: Q rows gathered at qsel. A[row=l15][k=(l4)*8+j]
  bf16x8 aq[3][2];
#pragma unroll
  for (int mf = 0; mf < 3; mf++) {
    const float* src = Qb + (size_t)qs[mf * 16 + l15] * D_ + l4 * 8;
#pragma unroll
    for (int ks = 0; ks < 2; ks++) {
      bf16x8 a;
#pragma unroll
      for (int j = 0; j < 8; j++) a[j] = (short)f2bf(src[ks * 32 + j]);
      aq[mf][ks] = a;
    }
  }

  int myq[3][4];
#pragma unroll
  for (int mf = 0; mf < 3; mf++)
#pragma unroll
    for (int rg = 0; rg < 4; rg++)
      myq[mf][rg] = qs[mf * 16 + l4 * 4 + rg];

  float m_r[3][4], l_r[3][4];
  f32x4 Oa[3][4];
  const f32x4 z4 = {0.f, 0.f, 0.f, 0.f};
#pragma unroll
  for (int mf = 0; mf < 3; mf++)
#pragma unroll
    for (int rg = 0; rg < 4; rg++) { m_r[mf][rg] = -1e30f; l_r[mf][rg] = 0.f; }
#pragma unroll
  for (int mf = 0; mf < 3; mf++)
#pragma unroll
    for (int df = 0; df < 4; df++) Oa[mf][df] = z4;

  for (int t = 0; t < 8; t++) {
    const int k0 = wave * 512 + t * 64;
    if (k0 > qmax) break;   // k0 ascending per wave; uniform within wave

    // ---- S = (Q K^T): B[kdim=d][col=key] = K[key][d]
    f32x4 S[3][4];
#pragma unroll
    for (int nf = 0; nf < 4; nf++) {
      const float* ksrc = Kb + (size_t)(k0 + nf * 16 + l15) * D_ + l4 * 8;
      bf16x8 bk0, bk1;
#pragma unroll
      for (int j = 0; j < 8; j++) bk0[j] = (short)f2bf(ksrc[j]);
#pragma unroll
      for (int j = 0; j < 8; j++) bk1[j] = (short)f2bf(ksrc[32 + j]);
#pragma unroll
      for (int mf = 0; mf < 3; mf++) {
        f32x4 c = z4;
        c = __builtin_amdgcn_mfma_f32_16x16x32_bf16(aq[mf][0], bk0, c, 0, 0, 0);
        c = __builtin_amdgcn_mfma_f32_16x16x32_bf16(aq[mf][1], bk1, c, 0, 0, 0);
        S[mf][nf] = c;
      }
    }

    // ---- scale + causal mask (col > qsel[row] -> -1e30)
#pragma unroll
    for (int mf = 0; mf < 3; mf++)
#pragma unroll
      for (int nf = 0; nf < 4; nf++) {
        const int kc = k0 + nf * 16 + l15;
#pragma unroll
        for (int rg = 0; rg < 4; rg++) {
          float v = S[mf][nf][rg] * 0.125f;
          S[mf][nf][rg] = (kc > myq[mf][rg]) ? -1e30f : v;
        }
      }

    // ---- V B-frags for this tile (shared across mf)
    bf16x8 vv[2][4];
#pragma unroll
    for (int ks = 0; ks < 2; ks++)
#pragma unroll
      for (int df = 0; df < 4; df++) {
        bf16x8 x;
#pragma unroll
        for (int j = 0; j < 8; j++)
          x[j] = (short)f2bf(Vb[(size_t)(k0 + ks * 32 + l4 * 8 + j) * D_ + df * 16 + l15]);
        vv[ks][df] = x;
      }

#pragma unroll
    for (int mf = 0; mf < 3; mf++) {
      // online-softmax stats update (row lives in 16 consecutive lanes)
#pragma unroll
      for (int rg = 0; rg < 4; rg++) {
        float tm = fmax(fmax(S[mf][0][rg], S[mf][1][rg]),
                        fmax(S[mf][2][rg], S[mf][3][rg]));
#pragma unroll
        for (int off = 1; off < 16; off <<= 1) tm = fmax(tm, __shfl_xor(tm, off));
        const float mn = fmax(m_r[mf][rg], tm);
        const float sc = __expf(m_r[mf][rg] - mn);   // (-1e30)-(-1e30)=0 -> 1
        l_r[mf][rg] *= sc;
#pragma unroll
        for (int df = 0; df < 4; df++) Oa[mf][df][rg] *= sc;
        m_r[mf][rg] = mn;
      }

      // p = exp(S - m), dead-row guarded; write P tile (C-layout) to LDS
      float rs[4] = {0.f, 0.f, 0.f, 0.f};
#pragma unroll
      for (int nf = 0; nf < 4; nf++)
#pragma unroll
        for (int rg = 0; rg < 4; rg++) {
          float p = __expf(S[mf][nf][rg] - m_r[mf][rg]);
          p = (m_r[mf][rg] > -1e29f) ? p : 0.f;
          rs[rg] += p;
          Pl[wave][l4 * 4 + rg][nf * 16 + l15] = f2bf(p);
        }
#pragma unroll
      for (int rg = 0; rg < 4; rg++) {
        float r = rs[rg];
#pragma unroll
        for (int off = 1; off < 16; off <<= 1) r += __shfl_xor(r, off);
        l_r[mf][rg] += r;
      }

      // PV: A-frag read back from LDS (row=l15, k=(l4)*8+j), accumulate O
#pragma unroll
      for (int ks = 0; ks < 2; ks++) {
        const bf16x8 pa = *(const bf16x8*)(&Pl[wave][l15][ks * 32 + l4 * 8]);
#pragma unroll
        for (int df = 0; df < 4; df++)
          Oa[mf][df] = __builtin_amdgcn_mfma_f32_16x16x32_bf16(pa, vv[ks][df], Oa[mf][df], 0, 0, 0);
      }
    }
  }

  // ---- cross-wave combine (deterministic)
  if (l15 == 0) {
#pragma unroll
    for (int mf = 0; mf < 3; mf++)
#pragma unroll
      for (int rg = 0; rg < 4; rg++) {
        const int row = mf * 16 + l4 * 4 + rg;
        mw[wave][row] = m_r[mf][rg];
        lw[wave][row] = l_r[mf][rg];
      }
  }
  __syncthreads();

  float sc_me[3][4];
#pragma unroll
  for (int mf = 0; mf < 3; mf++)
#pragma unroll
    for (int rg = 0; rg < 4; rg++) {
      const int row = mf * 16 + l4 * 4 + rg;
      float m = -1e30f;
#pragma unroll
      for (int w = 0; w < 8; w++) m = fmax(m, mw[w][row]);
      float ls = 0.f;
#pragma unroll
      for (int w = 0; w < 8; w++) ls += lw[w][row] * __expf(mw[w][row] - m);
      sc_me[mf][rg] = __expf(m_r[mf][rg] - m);   // 0 for dead waves
      if (wave == 0 && l15 == 0) lgf[row] = ls;
    }

  for (int w = 0; w < 8; w++) {
    __syncthreads();
    if (wave == w) {
#pragma unroll
      for (int mf = 0; mf < 3; mf++)
#pragma unroll
        for (int df = 0; df < 4; df++)
#pragma unroll
          for (int rg = 0; rg < 4; rg++)
            Osum[mf * 16 + l4 * 4 + rg][df * 16 + l15] += Oa[mf][df][rg] * sc_me[mf][rg];
    }
  }
  __syncthreads();

  for (int i = threadIdx.x; i < U_ * 64; i += 512) {
    const int r = i >> 6, d = i & 63;
    out[(((size_t)b * L_ + (size_t)qs[r]) * H_ + h) * D_ + d] = Osum[r][d] / lgf[r];
  }
}

// ---------------------------------------------------------------------------
extern "C" void kernel_launch(void* const* d_in, const int* in_sizes, int n_in,
                              void* d_out, int out_size, void* d_ws, size_t ws_size,
                              hipStream_t stream)
{
  const float* Q   = (const float*)d_in[0];
  const float* K   = (const float*)d_in[1];
  const float* V   = (const float*)d_in[2];
  const int*   idx = (const int*)d_in[3];
  float* out = (float*)d_out;

  const size_t m_bytes = (size_t)BH_ * L_ * sizeof(float);   // 4 MiB
  float* M    = (float*)d_ws;
  int*   qsel = (int*)((char*)d_ws + m_bytes);
  if (ws_size < m_bytes + (size_t)BH_ * UP_ * sizeof(int)) return;

  k_probM <<<32768, 256, 0, stream>>>(Q, K, idx, M);
  k_top45 <<<BH_,   256, 0, stream>>>(M, qsel);
  k_cumsum<<<BH_,   512, 0, stream>>>(V, out);
  k_attn  <<<BH_,   512, 0, stream>>>(Q, K, V, qsel, out);
}

// Round 8
// 1472.381 us; speedup vs baseline: 1.3328x; 1.3328x over previous
//
#include <hip/hip_runtime.h>
#include <hip/hip_bf16.h>

#define B_  32
#define H_  8
#define L_  4096
#define D_  64
#define BH_ 256
#define U_  45
#define UP_ 48

#define CHUNK_R 256          // K rows per LDS chunk
#define NCH     16           // k-chunks (16*256 = 4096)
#define QCH     1024         // queries per main block
#define NQC     4            // q-quarters per bh
#define NCELLS  1024         // 16 kchunk * 64 qgroup(64q)
#define NENT    (L_ * U_)    // 184320 (q,j) pairs, SHARED across bh

typedef float f32x4  __attribute__((ext_vector_type(4)));
typedef float f32x2  __attribute__((ext_vector_type(2)));
typedef short bf16x8 __attribute__((ext_vector_type(8)));

__device__ __forceinline__ unsigned short f2bf(float f) {
  unsigned u = __builtin_bit_cast(unsigned, f);
  u += 0x7fffu + ((u >> 16) & 1u);   // RNE; inputs finite
  return (unsigned short)(u >> 16);
}

// ---------------------------------------------------------------------------
// Prep (ONE block): bucket all 184320 (q,j) pairs into CSR cells
// (kchunk 0..15, qgroup 0..63). idx is shared across bh -> built once.
// Entry order within a cell is atomic-scrambled (fine: consumers use
// order-independent integer atomics). entry = (q<<8) | r_local.
// ---------------------------------------------------------------------------
__global__ __launch_bounds__(1024) void k_prep(
    const int* __restrict__ idxg, unsigned* __restrict__ cellbase,
    unsigned* __restrict__ entries)
{
  __shared__ unsigned cnt[NCELLS];
  const int t = threadIdx.x;
  cnt[t] = 0u;
  __syncthreads();
  for (int i = t; i < NENT; i += 1024) {
    const int q = i / U_;
    const int v = idxg[i];
    const int cell = ((v >> 8) << 6) | (q >> 6);
    atomicAdd(&cnt[cell], 1u);
  }
  __syncthreads();
  if (t == 0) {
    unsigned run = 0;
    for (int c = 0; c < NCELLS; c++) { cellbase[c] = run; run += cnt[c]; }
    cellbase[NCELLS] = run;
  }
  __syncthreads();
  cnt[t] = cellbase[t];                  // reuse as cursors
  __syncthreads();
  for (int i = t; i < NENT; i += 1024) {
    const int q = i / U_;
    const int v = idxg[i];
    const int cell = ((v >> 8) << 6) | (q >> 6);
    const unsigned slot = atomicAdd(&cnt[cell], 1u);
    entries[slot] = ((unsigned)q << 8) | (unsigned)(v & 255);
  }
}

// ---------------------------------------------------------------------------
// Kernel 1: M[bh][q] = max_j(QK) - mean_j(QK). The 12 GB K re-read flows
// through LDS (R7 lesson: global gathers are MSHR-bound ~3cyc/64B-seg).
// Block = (bh, q-quarter of 1024). K chunk (256 rows, 64 KB) double-buffered
// via global_load_lds with 16B source pre-swizzle (slot^(r&15)) so quad
// b64 reads spread banks (~4-way). Quad per entry, flat loop, no divergence,
// no cross-iteration register state (allocator-proof). Q from global: entries
// bucketed in 64-q (16 KB) L1-resident windows. Per-q max/sum via LDS integer
// atomics in 2^20 fixed point: associative -> deterministic despite entry
// scramble; quantization 1e-6 << 1e-2 selection gaps.
// XCD-affine bid map: all 4 q-quarters of a bh on one XCD (K read once/L2).
// ---------------------------------------------------------------------------
__global__ __launch_bounds__(1024) void k_probM(
    const float* __restrict__ Qg, const float* __restrict__ Kg,
    const unsigned* __restrict__ cellbase, const unsigned* __restrict__ entries,
    float* __restrict__ Mg)
{
  const int bid = blockIdx.x;            // 1024 blocks
  const int xcd = bid & 7, kk = bid >> 3;
  const int bh  = xcd + ((kk >> 2) << 3);
  const int qc  = kk & 3;

  __shared__ float kbuf[2][CHUNK_R * 64];        // 2 x 64 KB
  __shared__ int                smax[QCH];       // 4 KB
  __shared__ unsigned long long ssum[QCH];       // 8 KB

  const int t = threadIdx.x;
  smax[t] = (int)0x80000000;
  ssum[t] = 0ull;

  const float* Kb = Kg + (size_t)bh * (L_ * D_);

  // Stage chunk kc into kbuf[bsel]: LDS unit l (16B) holds source unit
  // u = (l&15) ^ (r&15) of row r = l>>4  (pre-swizzled source, linear dest
  // as global_load_lds requires: dest = wavebase + lane*16).
#define STAGE(KC, BSEL) do { \
    _Pragma("unroll") \
    for (int uu = 0; uu < 4; uu++) { \
      const int l_  = t + uu * 1024; \
      const int r_  = l_ >> 4, p_ = l_ & 15; \
      const int us_ = p_ ^ (r_ & 15); \
      const float* src_ = Kb + ((size_t)((KC) * CHUNK_R + r_)) * 64 + us_ * 4; \
      __builtin_amdgcn_global_load_lds( \
          (const __attribute__((address_space(1))) void*)src_, \
          (__attribute__((address_space(3))) void*)(&kbuf[BSEL][0] + l_ * 4), \
          16, 0, 0); \
    } \
  } while (0)

  STAGE(0, 0);
  __syncthreads();                       // compiler drains vmcnt before barrier

  const int quad = t >> 2, lq = t & 3;
  const int qf0  = qc * 16;              // first qgroup of this block

  for (int kc = 0; kc < NCH; kc++) {
    const int cur = kc & 1;
    if (kc + 1 < NCH) STAGE(kc + 1, cur ^ 1);

    const unsigned e0 = cellbase[(kc << 6) + qf0];
    const unsigned e1 = cellbase[(kc << 6) + qf0 + 16];

    for (unsigned e = e0 + quad; e < e1; e += 256) {
      const unsigned ent = entries[e];
      const int q = (int)(ent >> 8);     // global q (within this quarter)
      const int r = (int)(ent & 255u);

      const float* qp = Qg + ((size_t)bh * L_ + q) * 64 + lq * 16;
      const f32x4 qa = *(const f32x4*)(qp);
      const f32x4 qb = *(const f32x4*)(qp + 4);
      const f32x4 qcv= *(const f32x4*)(qp + 8);
      const f32x4 qd = *(const f32x4*)(qp + 12);

      const float* kb0 = &kbuf[cur][r * 64];
      const int rx = r & 15;
      const int u0 = (lq * 4 + 0) ^ rx;
      const int u1 = (lq * 4 + 1) ^ rx;
      const int u2 = (lq * 4 + 2) ^ rx;
      const int u3 = (lq * 4 + 3) ^ rx;
      const f32x2 k0a = *(const f32x2*)(kb0 + u0 * 4);
      const f32x2 k0b = *(const f32x2*)(kb0 + u0 * 4 + 2);
      const f32x2 k1a = *(const f32x2*)(kb0 + u1 * 4);
      const f32x2 k1b = *(const f32x2*)(kb0 + u1 * 4 + 2);
      const f32x2 k2a = *(const f32x2*)(kb0 + u2 * 4);
      const f32x2 k2b = *(const f32x2*)(kb0 + u2 * 4 + 2);
      const f32x2 k3a = *(const f32x2*)(kb0 + u3 * 4);
      const f32x2 k3b = *(const f32x2*)(kb0 + u3 * 4 + 2);

      float d0 = 0.f, d1 = 0.f;
      d0 = fmaf(qa[0], k0a[0], d0); d1 = fmaf(qa[1], k0a[1], d1);
      d0 = fmaf(qa[2], k0b[0], d0); d1 = fmaf(qa[3], k0b[1], d1);
      d0 = fmaf(qb[0], k1a[0], d0); d1 = fmaf(qb[1], k1a[1], d1);
      d0 = fmaf(qb[2], k1b[0], d0); d1 = fmaf(qb[3], k1b[1], d1);
      d0 = fmaf(qcv[0], k2a[0], d0); d1 = fmaf(qcv[1], k2a[1], d1);
      d0 = fmaf(qcv[2], k2b[0], d0); d1 = fmaf(qcv[3], k2b[1], d1);
      d0 = fmaf(qd[0], k3a[0], d0); d1 = fmaf(qd[1], k3a[1], d1);
      d0 = fmaf(qd[2], k3b[0], d0); d1 = fmaf(qd[3], k3b[1], d1);
      float dot = d0 + d1;
      dot += __shfl_xor(dot, 1);
      dot += __shfl_xor(dot, 2);

      if (lq == 0) {
        const int fx = (int)rintf(dot * 1048576.0f);   // 2^20 fixed point
        atomicMax(&smax[q & (QCH - 1)], fx);
        atomicAdd(&ssum[q & (QCH - 1)], (unsigned long long)(long long)fx);
      }
    }
    __syncthreads();                     // drains staged loads + LDS reads
  }
#undef STAGE

  {
    const double inv = 1.0 / 1048576.0;
    const double mx = (double)smax[t] * inv;
    const double sm = (double)(long long)ssum[t] * inv;
    Mg[(size_t)bh * L_ + qc * QCH + t] = (float)(mx - sm / 45.0);
  }
}

// ---------------------------------------------------------------------------
// Kernel 2: top-45 indices per (b,h) via 45 iterative block argmax passes.
// Writes 48 entries (3 pads = sels[0], harmlessly recomputed in k_attn).
// ---------------------------------------------------------------------------
__global__ __launch_bounds__(256) void k_top45(
    const float* __restrict__ Mg, int* __restrict__ qselg)
{
  __shared__ float mv[L_];
  __shared__ float rv[256];
  __shared__ int   ri[256];
  __shared__ int   sels[UP_];
  const int bh = blockIdx.x, t = threadIdx.x;

  for (int i = t; i < L_; i += 256) mv[i] = Mg[(size_t)bh * L_ + i];
  __syncthreads();

  for (int it = 0; it < U_; it++) {
    float bv = -3.4e38f; int bi = 0;
    for (int i = t; i < L_; i += 256) {
      float v = mv[i];
      if (v > bv) { bv = v; bi = i; }
    }
    rv[t] = bv; ri[t] = bi;
    __syncthreads();
    for (int s = 128; s > 0; s >>= 1) {
      if (t < s) {
        float ov = rv[t + s];
        if (ov > rv[t] || (ov == rv[t] && ri[t + s] < ri[t])) {
          rv[t] = ov; ri[t] = ri[t + s];
        }
      }
      __syncthreads();
    }
    if (t == 0) { sels[it] = ri[0]; mv[ri[0]] = -3.4e38f; }
    __syncthreads();
  }
  if (t == 0) { sels[45] = sels[0]; sels[46] = sels[0]; sels[47] = sels[0]; }
  __syncthreads();
  if (t < UP_) qselg[bh * UP_ + t] = sels[t];
}

// ---------------------------------------------------------------------------
// Kernel 3: context = cumsum(V, axis=L), written transposed to out[b,l,h,d].
// ---------------------------------------------------------------------------
__global__ __launch_bounds__(512) void k_cumsum(
    const float* __restrict__ Vg, float* __restrict__ out)
{
  const int bh = blockIdx.x, b = bh >> 3, h = bh & 7;
  const int d = threadIdx.x & 63, s = threadIdx.x >> 6;
  __shared__ float segsum[8][64];

  const float* vb = Vg + (size_t)bh * L_ * D_ + d;
  const int l0 = s * 512;

  float acc = 0.f;
  for (int l = l0; l < l0 + 512; l += 4) {
    float a0 = vb[(size_t)(l + 0) * D_];
    float a1 = vb[(size_t)(l + 1) * D_];
    float a2 = vb[(size_t)(l + 2) * D_];
    float a3 = vb[(size_t)(l + 3) * D_];
    acc += a0; acc += a1; acc += a2; acc += a3;
  }
  segsum[s][d] = acc;
  __syncthreads();

  float run = 0.f;
  for (int ss = 0; ss < s; ss++) run += segsum[ss][d];

  float* ob = out + ((size_t)b * L_ * H_ + h) * D_ + d;
  for (int l = l0; l < l0 + 512; l += 4) {
    float a0 = vb[(size_t)(l + 0) * D_];
    float a1 = vb[(size_t)(l + 1) * D_];
    float a2 = vb[(size_t)(l + 2) * D_];
    float a3 = vb[(size_t)(l + 3) * D_];
    run += a0; ob[(size_t)(l + 0) * (H_ * D_)] = run;
    run += a1; ob[(size_t)(l + 1) * (H_ * D_)] = run;
    run += a2; ob[(size_t)(l + 2) * (H_ * D_)] = run;
    run += a3; ob[(size_t)(l + 3) * (H_ * D_)] = run;
  }
}

// ---------------------------------------------------------------------------
// Kernel 4: flash attention for the 45 selected rows per (b,h), bf16 MFMA.
// ---------------------------------------------------------------------------
__global__ __launch_bounds__(512, 2) void k_attn(
    const float* __restrict__ Qg, const float* __restrict__ Kg,
    const float* __restrict__ Vg, const int* __restrict__ qselg,
    float* __restrict__ out)
{
  const int bh = blockIdx.x, b = bh >> 3, h = bh & 7;
  const int wave = threadIdx.x >> 6, lane = threadIdx.x & 63;
  const int l15 = lane & 15, l4 = lane >> 4;

  __shared__ int   qs[UP_];
  __shared__ float mw[8][UP_];
  __shared__ float lw[8][UP_];
  __shared__ float lgf[UP_];
  __shared__ float Osum[UP_][64];
  __shared__ unsigned short Pl[8][16][72];

  if (threadIdx.x < UP_) qs[threadIdx.x] = qselg[bh * UP_ + threadIdx.x];
  for (int i = threadIdx.x; i < UP_ * 64; i += 512) (&Osum[0][0])[i] = 0.f;
  __syncthreads();

  int qmax = 0;
  for (int r2 = 0; r2 < UP_; r2++) qmax = max(qmax, qs[r2]);

  const float* Qb = Qg + (size_t)bh * L_ * D_;
  const float* Kb = Kg + (size_t)bh * L_ * D_;
  const float* Vb = Vg + (size_t)bh * L_ * D_;

  bf16x8 aq[3][2];
#pragma unroll
  for (int mf = 0; mf < 3; mf++) {
    const float* src = Qb + (size_t)qs[mf * 16 + l15] * D_ + l4 * 8;
#pragma unroll
    for (int ks = 0; ks < 2; ks++) {
      bf16x8 a;
#pragma unroll
      for (int j = 0; j < 8; j++) a[j] = (short)f2bf(src[ks * 32 + j]);
      aq[mf][ks] = a;
    }
  }

  int myq[3][4];
#pragma unroll
  for (int mf = 0; mf < 3; mf++)
#pragma unroll
    for (int rg = 0; rg < 4; rg++)
      myq[mf][rg] = qs[mf * 16 + l4 * 4 + rg];

  float m_r[3][4], l_r[3][4];
  f32x4 Oa[3][4];
  const f32x4 z4 = {0.f, 0.f, 0.f, 0.f};
#pragma unroll
  for (int mf = 0; mf < 3; mf++)
#pragma unroll
    for (int rg = 0; rg < 4; rg++) { m_r[mf][rg] = -1e30f; l_r[mf][rg] = 0.f; }
#pragma unroll
  for (int mf = 0; mf < 3; mf++)
#pragma unroll
    for (int df = 0; df < 4; df++) Oa[mf][df] = z4;

  for (int t = 0; t < 8; t++) {
    const int k0 = wave * 512 + t * 64;
    if (k0 > qmax) break;

    f32x4 S[3][4];
#pragma unroll
    for (int nf = 0; nf < 4; nf++) {
      const float* ksrc = Kb + (size_t)(k0 + nf * 16 + l15) * D_ + l4 * 8;
      bf16x8 bk0, bk1;
#pragma unroll
      for (int j = 0; j < 8; j++) bk0[j] = (short)f2bf(ksrc[j]);
#pragma unroll
      for (int j = 0; j < 8; j++) bk1[j] = (short)f2bf(ksrc[32 + j]);
#pragma unroll
      for (int mf = 0; mf < 3; mf++) {
        f32x4 c = z4;
        c = __builtin_amdgcn_mfma_f32_16x16x32_bf16(aq[mf][0], bk0, c, 0, 0, 0);
        c = __builtin_amdgcn_mfma_f32_16x16x32_bf16(aq[mf][1], bk1, c, 0, 0, 0);
        S[mf][nf] = c;
      }
    }

#pragma unroll
    for (int mf = 0; mf < 3; mf++)
#pragma unroll
      for (int nf = 0; nf < 4; nf++) {
        const int kc = k0 + nf * 16 + l15;
#pragma unroll
        for (int rg = 0; rg < 4; rg++) {
          float v = S[mf][nf][rg] * 0.125f;
          S[mf][nf][rg] = (kc > myq[mf][rg]) ? -1e30f : v;
        }
      }

    bf16x8 vv[2][4];
#pragma unroll
    for (int ks = 0; ks < 2; ks++)
#pragma unroll
      for (int df = 0; df < 4; df++) {
        bf16x8 x;
#pragma unroll
        for (int j = 0; j < 8; j++)
          x[j] = (short)f2bf(Vb[(size_t)(k0 + ks * 32 + l4 * 8 + j) * D_ + df * 16 + l15]);
        vv[ks][df] = x;
      }

#pragma unroll
    for (int mf = 0; mf < 3; mf++) {
#pragma unroll
      for (int rg = 0; rg < 4; rg++) {
        float tm = fmax(fmax(S[mf][0][rg], S[mf][1][rg]),
                        fmax(S[mf][2][rg], S[mf][3][rg]));
#pragma unroll
        for (int off = 1; off < 16; off <<= 1) tm = fmax(tm, __shfl_xor(tm, off));
        const float mn = fmax(m_r[mf][rg], tm);
        const float sc = __expf(m_r[mf][rg] - mn);
        l_r[mf][rg] *= sc;
#pragma unroll
        for (int df = 0; df < 4; df++) Oa[mf][df][rg] *= sc;
        m_r[mf][rg] = mn;
      }

      float rs[4] = {0.f, 0.f, 0.f, 0.f};
#pragma unroll
      for (int nf = 0; nf < 4; nf++)
#pragma unroll
        for (int rg = 0; rg < 4; rg++) {
          float p = __expf(S[mf][nf][rg] - m_r[mf][rg]);
          p = (m_r[mf][rg] > -1e29f) ? p : 0.f;
          rs[rg] += p;
          Pl[wave][l4 * 4 + rg][nf * 16 + l15] = f2bf(p);
        }
#pragma unroll
      for (int rg = 0; rg < 4; rg++) {
        float r = rs[rg];
#pragma unroll
        for (int off = 1; off < 16; off <<= 1) r += __shfl_xor(r, off);
        l_r[mf][rg] += r;
      }

#pragma unroll
      for (int ks = 0; ks < 2; ks++) {
        const bf16x8 pa = *(const bf16x8*)(&Pl[wave][l15][ks * 32 + l4 * 8]);
#pragma unroll
        for (int df = 0; df < 4; df++)
          Oa[mf][df] = __builtin_amdgcn_mfma_f32_16x16x32_bf16(pa, vv[ks][df], Oa[mf][df], 0, 0, 0);
      }
    }
  }

  if (l15 == 0) {
#pragma unroll
    for (int mf = 0; mf < 3; mf++)
#pragma unroll
      for (int rg = 0; rg < 4; rg++) {
        const int row = mf * 16 + l4 * 4 + rg;
        mw[wave][row] = m_r[mf][rg];
        lw[wave][row] = l_r[mf][rg];
      }
  }
  __syncthreads();

  float sc_me[3][4];
#pragma unroll
  for (int mf = 0; mf < 3; mf++)
#pragma unroll
    for (int rg = 0; rg < 4; rg++) {
      const int row = mf * 16 + l4 * 4 + rg;
      float m = -1e30f;
#pragma unroll
      for (int w = 0; w < 8; w++) m = fmax(m, mw[w][row]);
      float ls = 0.f;
#pragma unroll
      for (int w = 0; w < 8; w++) ls += lw[w][row] * __expf(mw[w][row] - m);
      sc_me[mf][rg] = __expf(m_r[mf][rg] - m);
      if (wave == 0 && l15 == 0) lgf[row] = ls;
    }

  for (int w = 0; w < 8; w++) {
    __syncthreads();
    if (wave == w) {
#pragma unroll
      for (int mf = 0; mf < 3; mf++)
#pragma unroll
        for (int df = 0; df < 4; df++)
#pragma unroll
          for (int rg = 0; rg < 4; rg++)
            Osum[mf * 16 + l4 * 4 + rg][df * 16 + l15] += Oa[mf][df][rg] * sc_me[mf][rg];
    }
  }
  __syncthreads();

  for (int i = threadIdx.x; i < U_ * 64; i += 512) {
    const int r = i >> 6, d = i & 63;
    out[(((size_t)b * L_ + (size_t)qs[r]) * H_ + h) * D_ + d] = Osum[r][d] / lgf[r];
  }
}

// ---------------------------------------------------------------------------
extern "C" void kernel_launch(void* const* d_in, const int* in_sizes, int n_in,
                              void* d_out, int out_size, void* d_ws, size_t ws_size,
                              hipStream_t stream)
{
  const float* Q   = (const float*)d_in[0];
  const float* K   = (const float*)d_in[1];
  const float* V   = (const float*)d_in[2];
  const int*   idx = (const int*)d_in[3];
  float* out = (float*)d_out;

  const size_t m_bytes    = (size_t)BH_ * L_ * sizeof(float);      // 4 MiB
  const size_t qsel_bytes = (size_t)BH_ * UP_ * sizeof(int);       // 48 KiB
  const size_t ent_bytes  = (size_t)NENT * sizeof(unsigned);       // 720 KiB
  const size_t cb_bytes   = (size_t)(NCELLS + 1) * sizeof(unsigned);

  char* p = (char*)d_ws;
  float*    M        = (float*)p;                 p += m_bytes;
  int*      qsel     = (int*)p;                   p += qsel_bytes;
  unsigned* entries  = (unsigned*)p;              p += ent_bytes;
  unsigned* cellbase = (unsigned*)p;              p += cb_bytes;
  if (ws_size < (size_t)(p - (char*)d_ws)) return;

  k_prep  <<<1,    1024, 0, stream>>>(idx, cellbase, entries);
  k_probM <<<1024, 1024, 0, stream>>>(Q, K, cellbase, entries, M);
  k_top45 <<<BH_,  256,  0, stream>>>(M, qsel);
  k_cumsum<<<BH_,  512,  0, stream>>>(V, out);
  k_attn  <<<BH_,  512,  0, stream>>>(Q, K, V, qsel, out);
}

// Round 9
// 1438.879 us; speedup vs baseline: 1.3638x; 1.0233x over previous
//
#include <hip/hip_runtime.h>
#include <hip/hip_bf16.h>

#define B_  32
#define H_  8
#define L_  4096
#define D_  64
#define BH_ 256
#define U_  45
#define UP_ 48

#define CHUNK_R 128          // K rows per LDS chunk
#define NCH     32           // k-chunks (32*128 = 4096)
#define QCH     1024         // queries per main block
#define NCELLS  2048         // 32 kchunk * 64 qgroup(64q)
#define NENT    (L_ * U_)    // 184320 (q,j) pairs, SHARED across bh

typedef float f32x4  __attribute__((ext_vector_type(4)));
typedef float f32x2  __attribute__((ext_vector_type(2)));
typedef short bf16x8 __attribute__((ext_vector_type(8)));

__device__ __forceinline__ unsigned short f2bf(float f) {
  unsigned u = __builtin_bit_cast(unsigned, f);
  u += 0x7fffu + ((u >> 16) & 1u);   // RNE; inputs finite
  return (unsigned short)(u >> 16);
}

// ---------------------------------------------------------------------------
// Prep, parallelized (R8: single-block prep cost ~195us on one CU).
// Pass 1 (64 blocks): count entries per cell via global atomics.
// Pass 2 (1 block): exclusive prefix over 2048 cells -> cellbase + cursors.
// Pass 3 (64 blocks): scatter entries via global cursor atomics. Entry order
// within a cell is scrambled -- fine, consumers are order-independent.
// entry = (q<<8) | r_local(7b). cell = kchunk(5b)<<6 | qgroup(6b).
// ---------------------------------------------------------------------------
__global__ __launch_bounds__(1024) void k_pcount(
    const int* __restrict__ idxg, unsigned* __restrict__ gcnt)
{
  for (int i = blockIdx.x * 1024 + threadIdx.x; i < NENT; i += 64 * 1024) {
    const int q = i / U_;
    const int v = idxg[i];
    atomicAdd(&gcnt[((v >> 7) << 6) | (q >> 6)], 1u);
  }
}

__global__ __launch_bounds__(1024) void k_pscan(
    const unsigned* __restrict__ gcnt, unsigned* __restrict__ cellbase,
    unsigned* __restrict__ gcur)
{
  __shared__ unsigned v[NCELLS];
  const int t = threadIdx.x;
  v[t] = gcnt[t]; v[t + 1024] = gcnt[t + 1024];
  __syncthreads();
  if (t == 0) {
    unsigned run = 0;
    for (int c = 0; c < NCELLS; c++) {
      cellbase[c] = run; gcur[c] = run; run += v[c];
    }
    cellbase[NCELLS] = run;
  }
}

__global__ __launch_bounds__(1024) void k_pfill(
    const int* __restrict__ idxg, unsigned* __restrict__ gcur,
    unsigned* __restrict__ entries)
{
  for (int i = blockIdx.x * 1024 + threadIdx.x; i < NENT; i += 64 * 1024) {
    const int q = i / U_;
    const int v = idxg[i];
    const unsigned slot = atomicAdd(&gcur[((v >> 7) << 6) | (q >> 6)], 1u);
    entries[slot] = ((unsigned)q << 8) | (unsigned)(v & 127);
  }
}

// ---------------------------------------------------------------------------
// Kernel 1: M[bh][q] = max_j(QK) - mean_j(QK). K re-read flows through LDS
// (R7: global gathers are MSHR-bound). Block = (bh, q-quarter). K chunk of
// 128 rows (32 KB) double-buffered via global_load_lds, 16B source pre-
// swizzle (unit^(r&15)) so quad b64 reads spread banks. Quad per entry, flat
// loop, entry value prefetched one step ahead (single scalar -- nothing for
// the allocator to sink/spill). Per-q max/sum via LDS integer atomics in
// 2^20 fixed point (associative -> deterministic under entry scramble).
// LDS total 76 KB -> 2 blocks/CU (R8 was 143 KB -> 1 block, occupancy 48%):
// barriers and memory latency of one block hide under the other block.
// XCD-affine bid map: all 4 q-quarters of a bh on one XCD (K L2-resident).
// ---------------------------------------------------------------------------
__global__ __launch_bounds__(1024) void k_probM(
    const float* __restrict__ Qg, const float* __restrict__ Kg,
    const unsigned* __restrict__ cellbase, const unsigned* __restrict__ entries,
    float* __restrict__ Mg)
{
  const int bid = blockIdx.x;            // 1024 blocks
  const int xcd = bid & 7, kk = bid >> 3;
  const int bh  = xcd + ((kk >> 2) << 3);
  const int qc  = kk & 3;

  __shared__ float kbuf[2][CHUNK_R * 64];        // 2 x 32 KB
  __shared__ int                smax[QCH];       // 4 KB
  __shared__ unsigned long long ssum[QCH];       // 8 KB

  const int t = threadIdx.x;
  smax[t] = (int)0x80000000;
  ssum[t] = 0ull;

  const float* Kb = Kg + (size_t)bh * (L_ * D_);

  // LDS unit l holds source unit (l&15)^(r&15) of row r=l>>4 (pre-swizzled
  // source, linear dest as global_load_lds requires).
#define STAGE(KC, BSEL) do { \
    _Pragma("unroll") \
    for (int uu = 0; uu < 2; uu++) { \
      const int l_  = t + uu * 1024; \
      const int r_  = l_ >> 4, p_ = l_ & 15; \
      const int us_ = p_ ^ (r_ & 15); \
      const float* src_ = Kb + ((size_t)((KC) * CHUNK_R + r_)) * 64 + us_ * 4; \
      __builtin_amdgcn_global_load_lds( \
          (const __attribute__((address_space(1))) void*)src_, \
          (__attribute__((address_space(3))) void*)(&kbuf[BSEL][0] + l_ * 4), \
          16, 0, 0); \
    } \
  } while (0)

  STAGE(0, 0);
  __syncthreads();                       // compiler drains vmcnt before barrier

  const int quad = t >> 2, lq = t & 3;
  const int qf0  = qc * 16;              // first qgroup of this quarter

  for (int kc = 0; kc < NCH; kc++) {
    const int cur = kc & 1;
    if (kc + 1 < NCH) STAGE(kc + 1, cur ^ 1);

    const unsigned e0 = cellbase[(kc << 6) + qf0];
    const unsigned e1 = cellbase[(kc << 6) + qf0 + 16];

    unsigned e    = e0 + quad;
    bool     have = e < e1;
    unsigned ent  = have ? entries[e] : 0u;
    while (have) {
      const unsigned e2    = e + 256;
      const bool     have2 = e2 < e1;
      const unsigned ent2  = have2 ? entries[e2] : 0u;   // prefetch

      const int q = (int)(ent >> 8);
      const int r = (int)(ent & 127u);

      const float* qp = Qg + ((size_t)bh * L_ + q) * 64 + lq * 16;
      const f32x4 qa = *(const f32x4*)(qp);
      const f32x4 qb = *(const f32x4*)(qp + 4);
      const f32x4 qcv= *(const f32x4*)(qp + 8);
      const f32x4 qd = *(const f32x4*)(qp + 12);

      const float* kb0 = &kbuf[cur][r * 64];
      const int rx = r & 15;
      const int u0 = (lq * 4 + 0) ^ rx;
      const int u1 = (lq * 4 + 1) ^ rx;
      const int u2 = (lq * 4 + 2) ^ rx;
      const int u3 = (lq * 4 + 3) ^ rx;
      const f32x2 k0a = *(const f32x2*)(kb0 + u0 * 4);
      const f32x2 k0b = *(const f32x2*)(kb0 + u0 * 4 + 2);
      const f32x2 k1a = *(const f32x2*)(kb0 + u1 * 4);
      const f32x2 k1b = *(const f32x2*)(kb0 + u1 * 4 + 2);
      const f32x2 k2a = *(const f32x2*)(kb0 + u2 * 4);
      const f32x2 k2b = *(const f32x2*)(kb0 + u2 * 4 + 2);
      const f32x2 k3a = *(const f32x2*)(kb0 + u3 * 4);
      const f32x2 k3b = *(const f32x2*)(kb0 + u3 * 4 + 2);

      float d0 = 0.f, d1 = 0.f;
      d0 = fmaf(qa[0], k0a[0], d0); d1 = fmaf(qa[1], k0a[1], d1);
      d0 = fmaf(qa[2], k0b[0], d0); d1 = fmaf(qa[3], k0b[1], d1);
      d0 = fmaf(qb[0], k1a[0], d0); d1 = fmaf(qb[1], k1a[1], d1);
      d0 = fmaf(qb[2], k1b[0], d0); d1 = fmaf(qb[3], k1b[1], d1);
      d0 = fmaf(qcv[0], k2a[0], d0); d1 = fmaf(qcv[1], k2a[1], d1);
      d0 = fmaf(qcv[2], k2b[0], d0); d1 = fmaf(qcv[3], k2b[1], d1);
      d0 = fmaf(qd[0], k3a[0], d0); d1 = fmaf(qd[1], k3a[1], d1);
      d0 = fmaf(qd[2], k3b[0], d0); d1 = fmaf(qd[3], k3b[1], d1);
      float dot = d0 + d1;
      dot += __shfl_xor(dot, 1);
      dot += __shfl_xor(dot, 2);

      if (lq == 0) {
        const int fx = (int)rintf(dot * 1048576.0f);   // 2^20 fixed point
        atomicMax(&smax[q & (QCH - 1)], fx);
        atomicAdd(&ssum[q & (QCH - 1)], (unsigned long long)(long long)fx);
      }

      e = e2; ent = ent2; have = have2;
    }
    __syncthreads();                     // drains staged loads + LDS reads
  }
#undef STAGE

  {
    const double inv = 1.0 / 1048576.0;
    const double mx = (double)smax[t] * inv;
    const double sm = (double)(long long)ssum[t] * inv;
    Mg[(size_t)bh * L_ + qc * QCH + t] = (float)(mx - sm / 45.0);
  }
}

// ---------------------------------------------------------------------------
// Kernel 2: top-45 indices per (b,h) via 45 iterative block argmax passes.
// ---------------------------------------------------------------------------
__global__ __launch_bounds__(256) void k_top45(
    const float* __restrict__ Mg, int* __restrict__ qselg)
{
  __shared__ float mv[L_];
  __shared__ float rv[256];
  __shared__ int   ri[256];
  __shared__ int   sels[UP_];
  const int bh = blockIdx.x, t = threadIdx.x;

  for (int i = t; i < L_; i += 256) mv[i] = Mg[(size_t)bh * L_ + i];
  __syncthreads();

  for (int it = 0; it < U_; it++) {
    float bv = -3.4e38f; int bi = 0;
    for (int i = t; i < L_; i += 256) {
      float v = mv[i];
      if (v > bv) { bv = v; bi = i; }
    }
    rv[t] = bv; ri[t] = bi;
    __syncthreads();
    for (int s = 128; s > 0; s >>= 1) {
      if (t < s) {
        float ov = rv[t + s];
        if (ov > rv[t] || (ov == rv[t] && ri[t + s] < ri[t])) {
          rv[t] = ov; ri[t] = ri[t + s];
        }
      }
      __syncthreads();
    }
    if (t == 0) { sels[it] = ri[0]; mv[ri[0]] = -3.4e38f; }
    __syncthreads();
  }
  if (t == 0) { sels[45] = sels[0]; sels[46] = sels[0]; sels[47] = sels[0]; }
  __syncthreads();
  if (t < UP_) qselg[bh * UP_ + t] = sels[t];
}

// ---------------------------------------------------------------------------
// Kernel 3: context = cumsum(V, axis=L), written transposed to out[b,l,h,d].
// ---------------------------------------------------------------------------
__global__ __launch_bounds__(512) void k_cumsum(
    const float* __restrict__ Vg, float* __restrict__ out)
{
  const int bh = blockIdx.x, b = bh >> 3, h = bh & 7;
  const int d = threadIdx.x & 63, s = threadIdx.x >> 6;
  __shared__ float segsum[8][64];

  const float* vb = Vg + (size_t)bh * L_ * D_ + d;
  const int l0 = s * 512;

  float acc = 0.f;
  for (int l = l0; l < l0 + 512; l += 4) {
    float a0 = vb[(size_t)(l + 0) * D_];
    float a1 = vb[(size_t)(l + 1) * D_];
    float a2 = vb[(size_t)(l + 2) * D_];
    float a3 = vb[(size_t)(l + 3) * D_];
    acc += a0; acc += a1; acc += a2; acc += a3;
  }
  segsum[s][d] = acc;
  __syncthreads();

  float run = 0.f;
  for (int ss = 0; ss < s; ss++) run += segsum[ss][d];

  float* ob = out + ((size_t)b * L_ * H_ + h) * D_ + d;
  for (int l = l0; l < l0 + 512; l += 4) {
    float a0 = vb[(size_t)(l + 0) * D_];
    float a1 = vb[(size_t)(l + 1) * D_];
    float a2 = vb[(size_t)(l + 2) * D_];
    float a3 = vb[(size_t)(l + 3) * D_];
    run += a0; ob[(size_t)(l + 0) * (H_ * D_)] = run;
    run += a1; ob[(size_t)(l + 1) * (H_ * D_)] = run;
    run += a2; ob[(size_t)(l + 2) * (H_ * D_)] = run;
    run += a3; ob[(size_t)(l + 3) * (H_ * D_)] = run;
  }
}

// ---------------------------------------------------------------------------
// Kernel 4: flash attention for the 45 selected rows per (b,h), bf16 MFMA.
// ---------------------------------------------------------------------------
__global__ __launch_bounds__(512, 2) void k_attn(
    const float* __restrict__ Qg, const float* __restrict__ Kg,
    const float* __restrict__ Vg, const int* __restrict__ qselg,
    float* __restrict__ out)
{
  const int bh = blockIdx.x, b = bh >> 3, h = bh & 7;
  const int wave = threadIdx.x >> 6, lane = threadIdx.x & 63;
  const int l15 = lane & 15, l4 = lane >> 4;

  __shared__ int   qs[UP_];
  __shared__ float mw[8][UP_];
  __shared__ float lw[8][UP_];
  __shared__ float lgf[UP_];
  __shared__ float Osum[UP_][64];
  __shared__ unsigned short Pl[8][16][72];

  if (threadIdx.x < UP_) qs[threadIdx.x] = qselg[bh * UP_ + threadIdx.x];
  for (int i = threadIdx.x; i < UP_ * 64; i += 512) (&Osum[0][0])[i] = 0.f;
  __syncthreads();

  int qmax = 0;
  for (int r2 = 0; r2 < UP_; r2++) qmax = max(qmax, qs[r2]);

  const float* Qb = Qg + (size_t)bh * L_ * D_;
  const float* Kb = Kg + (size_t)bh * L_ * D_;
  const float* Vb = Vg + (size_t)bh * L_ * D_;

  bf16x8 aq[3][2];
#pragma unroll
  for (int mf = 0; mf < 3; mf++) {
    const float* src = Qb + (size_t)qs[mf * 16 + l15] * D_ + l4 * 8;
#pragma unroll
    for (int ks = 0; ks < 2; ks++) {
      bf16x8 a;
#pragma unroll
      for (int j = 0; j < 8; j++) a[j] = (short)f2bf(src[ks * 32 + j]);
      aq[mf][ks] = a;
    }
  }

  int myq[3][4];
#pragma unroll
  for (int mf = 0; mf < 3; mf++)
#pragma unroll
    for (int rg = 0; rg < 4; rg++)
      myq[mf][rg] = qs[mf * 16 + l4 * 4 + rg];

  float m_r[3][4], l_r[3][4];
  f32x4 Oa[3][4];
  const f32x4 z4 = {0.f, 0.f, 0.f, 0.f};
#pragma unroll
  for (int mf = 0; mf < 3; mf++)
#pragma unroll
    for (int rg = 0; rg < 4; rg++) { m_r[mf][rg] = -1e30f; l_r[mf][rg] = 0.f; }
#pragma unroll
  for (int mf = 0; mf < 3; mf++)
#pragma unroll
    for (int df = 0; df < 4; df++) Oa[mf][df] = z4;

  for (int t = 0; t < 8; t++) {
    const int k0 = wave * 512 + t * 64;
    if (k0 > qmax) break;

    f32x4 S[3][4];
#pragma unroll
    for (int nf = 0; nf < 4; nf++) {
      const float* ksrc = Kb + (size_t)(k0 + nf * 16 + l15) * D_ + l4 * 8;
      bf16x8 bk0, bk1;
#pragma unroll
      for (int j = 0; j < 8; j++) bk0[j] = (short)f2bf(ksrc[j]);
#pragma unroll
      for (int j = 0; j < 8; j++) bk1[j] = (short)f2bf(ksrc[32 + j]);
#pragma unroll
      for (int mf = 0; mf < 3; mf++) {
        f32x4 c = z4;
        c = __builtin_amdgcn_mfma_f32_16x16x32_bf16(aq[mf][0], bk0, c, 0, 0, 0);
        c = __builtin_amdgcn_mfma_f32_16x16x32_bf16(aq[mf][1], bk1, c, 0, 0, 0);
        S[mf][nf] = c;
      }
    }

#pragma unroll
    for (int mf = 0; mf < 3; mf++)
#pragma unroll
      for (int nf = 0; nf < 4; nf++) {
        const int kc = k0 + nf * 16 + l15;
#pragma unroll
        for (int rg = 0; rg < 4; rg++) {
          float v = S[mf][nf][rg] * 0.125f;
          S[mf][nf][rg] = (kc > myq[mf][rg]) ? -1e30f : v;
        }
      }

    bf16x8 vv[2][4];
#pragma unroll
    for (int ks = 0; ks < 2; ks++)
#pragma unroll
      for (int df = 0; df < 4; df++) {
        bf16x8 x;
#pragma unroll
        for (int j = 0; j < 8; j++)
          x[j] = (short)f2bf(Vb[(size_t)(k0 + ks * 32 + l4 * 8 + j) * D_ + df * 16 + l15]);
        vv[ks][df] = x;
      }

#pragma unroll
    for (int mf = 0; mf < 3; mf++) {
#pragma unroll
      for (int rg = 0; rg < 4; rg++) {
        float tm = fmax(fmax(S[mf][0][rg], S[mf][1][rg]),
                        fmax(S[mf][2][rg], S[mf][3][rg]));
#pragma unroll
        for (int off = 1; off < 16; off <<= 1) tm = fmax(tm, __shfl_xor(tm, off));
        const float mn = fmax(m_r[mf][rg], tm);
        const float sc = __expf(m_r[mf][rg] - mn);
        l_r[mf][rg] *= sc;
#pragma unroll
        for (int df = 0; df < 4; df++) Oa[mf][df][rg] *= sc;
        m_r[mf][rg] = mn;
      }

      float rs[4] = {0.f, 0.f, 0.f, 0.f};
#pragma unroll
      for (int nf = 0; nf < 4; nf++)
#pragma unroll
        for (int rg = 0; rg < 4; rg++) {
          float p = __expf(S[mf][nf][rg] - m_r[mf][rg]);
          p = (m_r[mf][rg] > -1e29f) ? p : 0.f;
          rs[rg] += p;
          Pl[wave][l4 * 4 + rg][nf * 16 + l15] = f2bf(p);
        }
#pragma unroll
      for (int rg = 0; rg < 4; rg++) {
        float r = rs[rg];
#pragma unroll
        for (int off = 1; off < 16; off <<= 1) r += __shfl_xor(r, off);
        l_r[mf][rg] += r;
      }

#pragma unroll
      for (int ks = 0; ks < 2; ks++) {
        const bf16x8 pa = *(const bf16x8*)(&Pl[wave][l15][ks * 32 + l4 * 8]);
#pragma unroll
        for (int df = 0; df < 4; df++)
          Oa[mf][df] = __builtin_amdgcn_mfma_f32_16x16x32_bf16(pa, vv[ks][df], Oa[mf][df], 0, 0, 0);
      }
    }
  }

  if (l15 == 0) {
#pragma unroll
    for (int mf = 0; mf < 3; mf++)
#pragma unroll
      for (int rg = 0; rg < 4; rg++) {
        const int row = mf * 16 + l4 * 4 + rg;
        mw[wave][row] = m_r[mf][rg];
        lw[wave][row] = l_r[mf][rg];
      }
  }
  __syncthreads();

  float sc_me[3][4];
#pragma unroll
  for (int mf = 0; mf < 3; mf++)
#pragma unroll
    for (int rg = 0; rg < 4; rg++) {
      const int row = mf * 16 + l4 * 4 + rg;
      float m = -1e30f;
#pragma unroll
      for (int w = 0; w < 8; w++) m = fmax(m, mw[w][row]);
      float ls = 0.f;
#pragma unroll
      for (int w = 0; w < 8; w++) ls += lw[w][row] * __expf(mw[w][row] - m);
      sc_me[mf][rg] = __expf(m_r[mf][rg] - m);
      if (wave == 0 && l15 == 0) lgf[row] = ls;
    }

  for (int w = 0; w < 8; w++) {
    __syncthreads();
    if (wave == w) {
#pragma unroll
      for (int mf = 0; mf < 3; mf++)
#pragma unroll
        for (int df = 0; df < 4; df++)
#pragma unroll
          for (int rg = 0; rg < 4; rg++)
            Osum[mf * 16 + l4 * 4 + rg][df * 16 + l15] += Oa[mf][df][rg] * sc_me[mf][rg];
    }
  }
  __syncthreads();

  for (int i = threadIdx.x; i < U_ * 64; i += 512) {
    const int r = i >> 6, d = i & 63;
    out[(((size_t)b * L_ + (size_t)qs[r]) * H_ + h) * D_ + d] = Osum[r][d] / lgf[r];
  }
}

// ---------------------------------------------------------------------------
extern "C" void kernel_launch(void* const* d_in, const int* in_sizes, int n_in,
                              void* d_out, int out_size, void* d_ws, size_t ws_size,
                              hipStream_t stream)
{
  const float* Q   = (const float*)d_in[0];
  const float* K   = (const float*)d_in[1];
  const float* V   = (const float*)d_in[2];
  const int*   idx = (const int*)d_in[3];
  float* out = (float*)d_out;

  const size_t m_bytes    = (size_t)BH_ * L_ * sizeof(float);      // 4 MiB
  const size_t qsel_bytes = (size_t)BH_ * UP_ * sizeof(int);       // 48 KiB
  const size_t ent_bytes  = (size_t)NENT * sizeof(unsigned);       // 720 KiB
  const size_t cb_bytes   = (size_t)(NCELLS + 1) * sizeof(unsigned);
  const size_t cnt_bytes  = (size_t)NCELLS * sizeof(unsigned);

  char* p = (char*)d_ws;
  float*    M        = (float*)p;                 p += m_bytes;
  int*      qsel     = (int*)p;                   p += qsel_bytes;
  unsigned* entries  = (unsigned*)p;              p += ent_bytes;
  unsigned* cellbase = (unsigned*)p;              p += cb_bytes;
  unsigned* gcnt     = (unsigned*)p;              p += cnt_bytes;
  unsigned* gcur     = (unsigned*)p;              p += cnt_bytes;
  if (ws_size < (size_t)(p - (char*)d_ws)) return;

  hipMemsetAsync(gcnt, 0, cnt_bytes, stream);
  k_pcount<<<64,   1024, 0, stream>>>(idx, gcnt);
  k_pscan <<<1,    1024, 0, stream>>>(gcnt, cellbase, gcur);
  k_pfill <<<64,   1024, 0, stream>>>(idx, gcur, entries);
  k_probM <<<1024, 1024, 0, stream>>>(Q, K, cellbase, entries, M);
  k_top45 <<<BH_,  256,  0, stream>>>(M, qsel);
  k_cumsum<<<BH_,  512,  0, stream>>>(V, out);
  k_attn  <<<BH_,  512,  0, stream>>>(Q, K, V, qsel, out);
}